// Round 8
// baseline (297.360 us; speedup 1.0000x reference)
//
#include <hip/hip_runtime.h>
#include <hip/hip_bf16.h>
#include <cstdint>
#include <cstddef>

typedef __bf16 bf16x8 __attribute__((ext_vector_type(8)));
typedef __bf16 bf16x4 __attribute__((ext_vector_type(4)));
typedef float f32x4 __attribute__((ext_vector_type(4)));

#define BATCH 16
#define MDIM 1024
#define NDIM 4096
#define KDIM 1024
#define BM 256
#define BN 256
#define BK 64
#define NKT (KDIM / BK)   // 16 K-tiles per pass
#define NPASS 4           // mt = 0..3 per block
#define NG (NKT * NPASS)  // 64 flattened tiles per block

__device__ __forceinline__ void gload_lds16(const void* g, void* l) {
  __builtin_amdgcn_global_load_lds(
      (const __attribute__((address_space(1))) void*)g,
      (__attribute__((address_space(3))) void*)l, 16, 0, 0);
}

#define BAR() __builtin_amdgcn_s_barrier()
#define SB() __builtin_amdgcn_sched_barrier(0)
#define FENCE() asm volatile("" ::: "memory")
#define LGKM0()                                        \
  do {                                                 \
    asm volatile("s_waitcnt lgkmcnt(0)" ::: "memory"); \
    SB();                                              \
  } while (0)
#define VMC32()                                        \
  do {                                                 \
    asm volatile("s_waitcnt vmcnt(32)" ::: "memory");  \
    SB();                                              \
  } while (0)

// ---------------------------------------------------------------------------
// Kernel 1: W~[b][o][i] bf16 into workspace (~10us).  (unchanged)
// ---------------------------------------------------------------------------
__global__ __launch_bounds__(256) void modw_kernel(
    const float* __restrict__ weight, const float* __restrict__ y,
    __bf16* __restrict__ wm) {
  const int blk = blockIdx.x;  // 16384
  const int b = blk & 15;
  const int o = blk >> 4;
  const int t = threadIdx.x;
  const float4 w4 = reinterpret_cast<const float4*>(weight + (size_t)o * KDIM)[t];
  const float4 y4 = reinterpret_cast<const float4*>(y + (size_t)b * KDIM)[t];
  const float p0 = w4.x * y4.x, p1 = w4.y * y4.y;
  const float p2 = w4.z * y4.z, p3 = w4.w * y4.w;
  float s = p0 * p0 + p1 * p1 + p2 * p2 + p3 * p3;
#pragma unroll
  for (int off = 32; off >= 1; off >>= 1) s += __shfl_xor(s, off, 64);
  __shared__ float ps[4];
  if ((t & 63) == 0) ps[t >> 6] = s;
  __syncthreads();
  const float tot = ps[0] + ps[1] + ps[2] + ps[3];
  const float scale = 0.03125f;  // 1/sqrt(1024)
  const float dn = scale * rsqrtf(scale * scale * tot + 1e-8f);
  bf16x4 v;
  v[0] = (__bf16)(p0 * dn);
  v[1] = (__bf16)(p1 * dn);
  v[2] = (__bf16)(p2 * dn);
  v[3] = (__bf16)(p3 * dn);
  *reinterpret_cast<bf16x4*>(wm + ((size_t)b * MDIM + o) * KDIM + t * 4) = v;
}

// ---------------------------------------------------------------------------
// Kernel 2: PERSISTENT fused GEMM.  Grid = 256 blocks (1/CU), each block owns
// one (b, nt) output column-stripe and loops mt = 0..3 IN-KERNEL as a single
// flattened 64-iteration K-loop (g = mt*16 + kt), R6 region rhythm unchanged.
// Why: at 128 KB LDS only 1 block resides per CU, so the old 4-sequential-
// block schedule paid (serial prologue drain + pipeline fill + epilogue
// drain + dispatch gap) x4 per CU with ZERO overlap.  Persistent form keeps
// stages/loads in flight across pass boundaries; epilogue stores overlap the
// next pass's prefetch.  E is mt-independent -> loadB/writeB/br carry across
// passes unchanged (and the block's 1MB E panel goes L2/L3-hot on passes
// 2-4).  Uniform wrapped prefetch indices: no tail conditionals; wrap-staged
// tiles land in buffers never consumed.  Numerics: per-pass identical to R6
// -> bit-identical output.  VMEM-queue invariant at the counted wait is the
// R6 one: [stageA(g+1) 4 older, br(g+2) 32 younger] -> vmcnt(32).
// ---------------------------------------------------------------------------
__global__ __launch_bounds__(512, 2) void gemm_kernel(
    const __bf16* __restrict__ Wm, const float* __restrict__ E,
    float* __restrict__ out) {
  const int blk = blockIdx.x;  // 256
  const int nt = blk & 15;
  const int b = blk >> 4;
  const int n0 = nt * BN;

  __shared__ __align__(16) char smem[131072];
  char* const A0_ = smem;
  char* const A1_ = smem + 32768;
  char* const B0_ = smem + 65536;
  char* const B1_ = smem + 98304;

  const int tid = threadIdx.x;  // 512
  const int lane = tid & 63;
  const int wid = tid >> 6;  // 0..7
  const int wr = wid >> 2;   // 0..1
  const int wc = wid & 3;    // 0..3
  const int ml = lane & 15;
  const int kg = lane >> 4;

  // ---- A staging (m-offset applied per flattened tile index) ----
  const int arow = tid >> 3;                      // 0..63, +64/round
  const int aswz = ((tid & 7) ^ (arow & 7)) * 8;  // pre-swizzled k-elem off
  const __bf16* Ag = Wm + ((size_t)(b * MDIM + arow)) * KDIM + aswz;
  const int aldsOff = tid * 16;

  // ---- B staging (mt-independent) ----
  const int bn1 = tid & 63;
  const int bkg = tid >> 6;
  typedef const __attribute__((address_space(1))) float gfloat;
  gfloat* Eg = (gfloat*)(E + (size_t)b * KDIM * NDIM +
                         (size_t)(bkg * 8) * NDIM + n0 + bn1);
  int bwr[4];
#pragma unroll
  for (int c = 0; c < 4; ++c) {
    const int n = bn1 + 64 * c;
    bwr[c] = n * 128 + ((bkg * 16) ^ ((n & 7) << 4));
  }

  // ---- compute-side fragment addressing ----
  const int colA = (kg * 16) ^ ((ml & 7) << 4);
  const int arB = (wr * 128 + ml) * 128;
  const int brB = (wc * 64 + ml) * 128;

  f32x4 acc[8][4];
#pragma unroll
  for (int i = 0; i < 8; ++i)
#pragma unroll
    for (int j = 0; j < 4; ++j) acc[i][j] = (f32x4){0.f, 0.f, 0.f, 0.f};

  auto stageA = [&](char* Ab, int g) {  // g = flattened tile index
    const int moff = ((g >> 4) & 3) * BM;
    const int kt = g & 15;
#pragma unroll
    for (int r = 0; r < 4; ++r)
      gload_lds16(Ag + (size_t)(moff + 64 * r) * KDIM + kt * BK,
                  Ab + aldsOff + r * 8192);
  };
  auto loadB = [&](float (&brr)[4][8], int g) {
    const int kt = g & 15;  // E independent of mt
#pragma unroll
    for (int c = 0; c < 4; ++c)
#pragma unroll
      for (int j = 0; j < 8; ++j)
        brr[c][j] = Eg[(size_t)(kt * BK + j) * NDIM + 64 * c];
  };
  auto writeB = [&](char* Bb, float (&brr)[4][8]) {
#pragma unroll
    for (int c = 0; c < 4; ++c) {
      bf16x8 v;
#pragma unroll
      for (int j = 0; j < 8; ++j) v[j] = (__bf16)brr[c][j];
      *reinterpret_cast<bf16x8*>(Bb + bwr[c]) = v;
    }
  };
  auto rdA = [&](bf16x8 (&d)[4], const char* Ab, int qm, int kk) {
#pragma unroll
    for (int i = 0; i < 4; ++i)
      d[i] = *reinterpret_cast<const bf16x8*>(Ab + arB + (qm * 4 + i) * 2048 +
                                              (colA ^ (kk * 64)));
  };
  auto rdB = [&](bf16x8 (&d)[4], const char* Bb, int kk) {
#pragma unroll
    for (int nf = 0; nf < 4; ++nf)
      d[nf] = *reinterpret_cast<const bf16x8*>(Bb + brB + nf * 2048 +
                                               (colA ^ (kk * 64)));
  };
  auto mfma16 = [&](bf16x8 (&a)[4], bf16x8 (&bv)[4], int qm) {
    __builtin_amdgcn_s_setprio(1);
#pragma unroll
    for (int i = 0; i < 4; ++i)
#pragma unroll
      for (int nf = 0; nf < 4; ++nf)
        acc[qm * 4 + i][nf] = __builtin_amdgcn_mfma_f32_16x16x32_bf16(
            a[i], bv[nf], acc[qm * 4 + i][nf], 0, 0, 0);
    __builtin_amdgcn_s_setprio(0);
  };

  float br[4][8];          // B reg-stage, persistent (valid across passes)
  bf16x8 af0[4], af1[4];   // rotating frag slots
  bf16x8 bf0[4], bf1[4];

  // ---- prologue (once per block): tile g=0 -> A0/B0; br <- g=1 ----
  {
    float brT[4][8];
    stageA(A0_, 0);  // queue [A0(4)]
    FENCE();
    loadB(brT, 0);     // [A0(4), brT(32)]
    writeB(B0_, brT);  // implicit vmcnt(0): all drained (once per block)
    loadB(br, 1);      // [br(1) 32] == loop-entry invariant
    LGKM0();
    BAR();
    rdA(af0, A0_, 0, 0);  // read-ahead for g=0 R0
    rdB(bf0, B0_, 0);
  }

  char* Acur = A0_;
  char* Ao = A1_;
  char* Bc = B0_;
  char* Bo = B1_;

#pragma unroll 1
  for (int g = 0; g < NG; ++g) {
    const int g1 = (g + 1) & (NG - 1);  // wrapped: uniform, no tail branches
    const int g2 = (g + 2) & (NG - 1);

    // R0: read-ahead (q1,k0); publish B(g+1); MFMA q0k0
    rdA(af1, Acur, 1, 0);
    writeB(Bo, br);  // implicit wait: br(g+1), issued last iteration
    mfma16(af0, bf0, 0);

    // R1: read-ahead (k1),(q0,k1); stage A(g+1); prefetch br(g+2); MFMA q1k0
    rdB(bf1, Bc, 1);
    rdA(af0, Acur, 0, 1);
    stageA(Ao, g1);
    FENCE();  // pin VMEM order: stage older than br loads
    loadB(br, g2);
    mfma16(af1, bf0, 1);

    // R2: read-ahead (q1,k1); MFMA q0k1; single sync point per tile
    rdA(af1, Acur, 1, 1);
    mfma16(af0, bf1, 0);
    LGKM0();  // my frag reads + my B ds_writes done
    VMC32();  // queue [stageA(g+1) 4 | br(g+2) 32] -> drains the A stage
    BAR();

    // R3: read-ahead next tile's frags from Ao/Bo; MFMA q1k1
    rdA(af0, Ao, 0, 0);
    rdB(bf0, Bo, 0);
    mfma16(af1, bf1, 1);

    // ---- inline per-pass epilogue: stores overlap next pass's in-flight
    //      prefetch (stage(g+1)/br(g+2) already issued above) ----
    if ((g & 15) == 15) {
      const int mt = g >> 4;
      float* ob = out +
                  ((size_t)(b * MDIM + mt * BM + wr * 128 + kg * 4)) * NDIM +
                  n0 + wc * 64 + ml;
#pragma unroll
      for (int mf = 0; mf < 8; ++mf)
#pragma unroll
        for (int nf = 0; nf < 4; ++nf) {
          const f32x4 a = acc[mf][nf];
          float* p = ob + (size_t)mf * 16 * NDIM + nf * 16;
#pragma unroll
          for (int q = 0; q < 4; ++q) p[(size_t)q * NDIM] = a[q];
        }
#pragma unroll
      for (int i = 0; i < 8; ++i)
#pragma unroll
        for (int j = 0; j < 4; ++j) acc[i][j] = (f32x4){0.f, 0.f, 0.f, 0.f};
    }

    // rotate buffers
    char* ta = Acur; Acur = Ao; Ao = ta;
    char* tb = Bc; Bc = Bo; Bo = tb;
  }
}

extern "C" void kernel_launch(void* const* d_in, const int* in_sizes, int n_in,
                              void* d_out, int out_size, void* d_ws,
                              size_t ws_size, hipStream_t stream) {
  (void)in_sizes;
  (void)n_in;
  (void)out_size;
  (void)ws_size;
  const float* Efou = (const float*)d_in[0];
  const float* y = (const float*)d_in[1];
  const float* weight = (const float*)d_in[2];
  float* outp = (float*)d_out;
  __bf16* wm = (__bf16*)d_ws;  // 32 MB

  modw_kernel<<<dim3(BATCH * MDIM), dim3(256), 0, stream>>>(weight, y, wm);
  gemm_kernel<<<dim3(BATCH * (NDIM / BN)), dim3(512), 0, stream>>>(wm, Efou,
                                                                   outp);
}

// Round 9
// 248.838 us; speedup vs baseline: 1.1950x; 1.1950x over previous
//
#include <hip/hip_runtime.h>
#include <hip/hip_bf16.h>
#include <cstdint>
#include <cstddef>

typedef __bf16 bf16x8 __attribute__((ext_vector_type(8)));
typedef __bf16 bf16x4 __attribute__((ext_vector_type(4)));
typedef float f32x4 __attribute__((ext_vector_type(4)));

#define BATCH 16
#define MDIM 1024
#define NDIM 4096
#define KDIM 1024
#define BM 128
#define BN 128
#define BK 64
#define NKT (KDIM / BK)  // 16

__device__ __forceinline__ void gload_lds16(const void* g, void* l) {
  __builtin_amdgcn_global_load_lds(
      (const __attribute__((address_space(1))) void*)g,
      (__attribute__((address_space(3))) void*)l, 16, 0, 0);
}

#define BAR() __builtin_amdgcn_s_barrier()
#define SB() __builtin_amdgcn_sched_barrier(0)
#define FENCE() asm volatile("" ::: "memory")
#define LGKM0()                                        \
  do {                                                 \
    asm volatile("s_waitcnt lgkmcnt(0)" ::: "memory"); \
    SB();                                              \
  } while (0)

// ---------------------------------------------------------------------------
// Kernel 1: W~[b][o][i] bf16 into workspace (~10us).  (unchanged)
// ---------------------------------------------------------------------------
__global__ __launch_bounds__(256) void modw_kernel(
    const float* __restrict__ weight, const float* __restrict__ y,
    __bf16* __restrict__ wm) {
  const int blk = blockIdx.x;  // 16384
  const int b = blk & 15;
  const int o = blk >> 4;
  const int t = threadIdx.x;
  const float4 w4 = reinterpret_cast<const float4*>(weight + (size_t)o * KDIM)[t];
  const float4 y4 = reinterpret_cast<const float4*>(y + (size_t)b * KDIM)[t];
  const float p0 = w4.x * y4.x, p1 = w4.y * y4.y;
  const float p2 = w4.z * y4.z, p3 = w4.w * y4.w;
  float s = p0 * p0 + p1 * p1 + p2 * p2 + p3 * p3;
#pragma unroll
  for (int off = 32; off >= 1; off >>= 1) s += __shfl_xor(s, off, 64);
  __shared__ float ps[4];
  if ((t & 63) == 0) ps[t >> 6] = s;
  __syncthreads();
  const float tot = ps[0] + ps[1] + ps[2] + ps[3];
  const float scale = 0.03125f;  // 1/sqrt(1024)
  const float dn = scale * rsqrtf(scale * scale * tot + 1e-8f);
  bf16x4 v;
  v[0] = (__bf16)(p0 * dn);
  v[1] = (__bf16)(p1 * dn);
  v[2] = (__bf16)(p2 * dn);
  v[3] = (__bf16)(p3 * dn);
  *reinterpret_cast<bf16x4*>(wm + ((size_t)b * MDIM + o) * KDIM + t * 4) = v;
}

// ---------------------------------------------------------------------------
// Kernel 2: 128x128x64 tiles, 256 threads (4 waves, 2x2), 48 KB LDS
// (A double-buffered 2x16 KB + B single-buffered 16 KB) -> 3 blocks/CU
// (LDS: 3x48=144<=160; regs: ~88 VGPR + 64 acc = 152 <= 170 for 3 waves/EU,
// pinned by __launch_bounds__(256,3)).  Mechanism: every lockstep-schedule
// variation at 2 waves/SIMD was null (R2/R5/R6/R7) because both waves share
// each barrier; 3 INDEPENDENT blocks per CU give each SIMD 3 waves with
// uncorrelated sync points, so one block's MFMA covers another's staging
// stalls.  R3's version of this failed mechanically (64 KB dbuf LDS capped
// residency at 2 blocks); B single-buffering fixes that at the cost of one
// extra post-compute barrier per tile (hidden by cross-block overlap).
// Per-tile schedule:
//   stageA(A[nxt],t+1); loadB(br,t+1)   [VMEM ages a full compute phase]
//   compute tile t (2kk x {4 bf + 4 af reads, 16 MFMA, setprio})
//   BAR; writeB(B,br) [implicit drain: all in-queue loads are old];
//   LGKM0; BAR; swap A buffers
// Numerics: same K-order / cvt points as all passing rounds -> bit-identical.
// ---------------------------------------------------------------------------
__global__ __launch_bounds__(256, 3) void gemm_kernel(
    const __bf16* __restrict__ Wm, const float* __restrict__ E,
    float* __restrict__ out) {
  const int orig = blockIdx.x;  // 4096
  const int wg = (orig & 7) * 512 + (orig >> 3);  // bijective XCD swizzle
  const int mt = wg & 7;          // 8 m-tiles: consecutive wg share E panel
  const int nt = (wg >> 3) & 31;  // 32 n-tiles
  const int b = wg >> 8;
  const int m0 = mt * BM, n0 = nt * BN;

  __shared__ __align__(16) char smem[49152];
  char* const A0_ = smem;
  char* const A1_ = smem + 16384;
  char* const B_ = smem + 32768;

  const int tid = threadIdx.x;  // 256
  const int lane = tid & 63;
  const int wid = tid >> 6;  // 0..3
  const int wr = wid >> 1;   // 0..1  (64 rows each)
  const int wc = wid & 1;    // 0..1  (64 cols each)
  const int ml = lane & 15;
  const int kg = lane >> 4;

  // ---- A staging: 128x64 bf16 = 16 KB/tile, 4 gload_lds rounds ----
  const int arow = tid >> 3;                      // 0..31, +32/round
  const int aswz = ((tid & 7) ^ (arow & 7)) * 8;  // pre-swizzled k-elem off
  const __bf16* Ag = Wm + ((size_t)(b * MDIM + m0 + arow)) * KDIM + aswz;
  const int aldsOff = tid * 16;

  // ---- B staging: 128n x 64k fp32 loads -> bf16 [128n][64k] LDS ----
  const int bn1 = tid & 63;
  const int bkg = tid >> 6;  // 0..3
  typedef const __attribute__((address_space(1))) float gfloat;
  gfloat* Eg = (gfloat*)(E + (size_t)b * KDIM * NDIM +
                         (size_t)(bkg * 8) * NDIM + n0 + bn1);
  int bwr[4];  // [c*2+h]
#pragma unroll
  for (int c = 0; c < 2; ++c)
#pragma unroll
    for (int h = 0; h < 2; ++h) {
      const int n = bn1 + 64 * c;
      const int kbyte = bkg * 16 + h * 64;
      bwr[c * 2 + h] = n * 128 + (kbyte ^ ((n & 7) << 4));
    }

  // ---- compute-side fragment addressing ----
  const int colA = (kg * 16) ^ ((ml & 7) << 4);
  const int arB = (wr * 64 + ml) * 128;
  const int brB = (wc * 64 + ml) * 128;

  f32x4 acc[4][4];
#pragma unroll
  for (int i = 0; i < 4; ++i)
#pragma unroll
    for (int j = 0; j < 4; ++j) acc[i][j] = (f32x4){0.f, 0.f, 0.f, 0.f};

  auto stageA = [&](char* Ab, int kt) {
#pragma unroll
    for (int r = 0; r < 4; ++r)
      gload_lds16(Ag + (size_t)(32 * r) * KDIM + kt * BK,
                  Ab + aldsOff + r * 4096);
  };
  auto loadB = [&](float (&brr)[4][8], int kt) {
#pragma unroll
    for (int c = 0; c < 2; ++c)
#pragma unroll
      for (int h = 0; h < 2; ++h)
#pragma unroll
        for (int j = 0; j < 8; ++j)
          brr[c * 2 + h][j] =
              Eg[(size_t)(kt * BK + h * 32 + j) * NDIM + 64 * c];
  };
  auto writeB = [&](char* Bb, float (&brr)[4][8]) {
#pragma unroll
    for (int g = 0; g < 4; ++g) {
      bf16x8 v;
#pragma unroll
      for (int j = 0; j < 8; ++j) v[j] = (__bf16)brr[g][j];
      *reinterpret_cast<bf16x8*>(Bb + bwr[g]) = v;
    }
  };

  float br[4][8];  // B reg-stage (32 VGPR)

  // ---- prologue: tile 0 -> A0/B (full drain once) ----
  {
    float brT[4][8];
    stageA(A0_, 0);  // queue [A0(4)]
    FENCE();
    loadB(brT, 0);     // [A0(4), brT(32)]
    writeB(B_, brT);   // implicit wait drains everything
    LGKM0();
    BAR();
  }

  char* Ac = A0_;
  char* An = A1_;

#pragma unroll 1
  for (int t = 0; t < NKT; ++t) {
    const bool pf = (t + 1 < NKT);

    // issue next tile's VMEM first: ages a full compute phase before use
    if (pf) {
      stageA(An, t + 1);  // -> LDS A[nxt] (not read this tile)
      FENCE();            // pin order: stage older than br loads
      loadB(br, t + 1);   // -> regs
    }

    // compute tile t from Ac / B
#pragma unroll
    for (int kk = 0; kk < 2; ++kk) {
      const int kx = colA ^ (kk * 64);
      bf16x8 af[4], bf[4];
#pragma unroll
      for (int nf = 0; nf < 4; ++nf)
        bf[nf] = *reinterpret_cast<const bf16x8*>(B_ + brB + nf * 2048 + kx);
#pragma unroll
      for (int i = 0; i < 4; ++i)
        af[i] = *reinterpret_cast<const bf16x8*>(Ac + arB + i * 2048 + kx);
      __builtin_amdgcn_s_setprio(1);
#pragma unroll
      for (int i = 0; i < 4; ++i)
#pragma unroll
        for (int nf = 0; nf < 4; ++nf)
          acc[i][nf] = __builtin_amdgcn_mfma_f32_16x16x32_bf16(
              af[i], bf[nf], acc[i][nf], 0, 0, 0);
      __builtin_amdgcn_s_setprio(0);
    }

    BAR();  // all waves done reading B(t) and Ac(t)

    if (pf) {
      writeB(B_, br);  // implicit vmcnt wait: br + stage both ~1 phase old
      LGKM0();         // B ds_writes visible; (A stage drained by br wait)
      BAR();           // B(t+1) + A[nxt] ready for all waves
    }

    char* ta = Ac; Ac = An; An = ta;
  }

  // ---- epilogue ----
  float* ob = out + ((size_t)(b * MDIM + m0 + wr * 64 + kg * 4)) * NDIM +
              n0 + wc * 64 + ml;
#pragma unroll
  for (int mf = 0; mf < 4; ++mf)
#pragma unroll
    for (int nf = 0; nf < 4; ++nf) {
      const f32x4 a = acc[mf][nf];
      float* p = ob + (size_t)mf * 16 * NDIM + nf * 16;
#pragma unroll
      for (int q = 0; q < 4; ++q) p[(size_t)q * NDIM] = a[q];
    }
}

extern "C" void kernel_launch(void* const* d_in, const int* in_sizes, int n_in,
                              void* d_out, int out_size, void* d_ws,
                              size_t ws_size, hipStream_t stream) {
  (void)in_sizes;
  (void)n_in;
  (void)out_size;
  (void)ws_size;
  const float* Efou = (const float*)d_in[0];
  const float* y = (const float*)d_in[1];
  const float* weight = (const float*)d_in[2];
  float* outp = (float*)d_out;
  __bf16* wm = (__bf16*)d_ws;  // 32 MB

  modw_kernel<<<dim3(BATCH * MDIM), dim3(256), 0, stream>>>(weight, y, wm);
  gemm_kernel<<<dim3(BATCH * (MDIM / BM) * (NDIM / BN)), dim3(256), 0,
                stream>>>(wm, Efou, outp);
}

// Round 10
// 241.467 us; speedup vs baseline: 1.2315x; 1.0305x over previous
//
#include <hip/hip_runtime.h>
#include <hip/hip_bf16.h>
#include <cstdint>
#include <cstddef>

typedef __bf16 bf16x8 __attribute__((ext_vector_type(8)));
typedef __bf16 bf16x4 __attribute__((ext_vector_type(4)));
typedef float f32x4 __attribute__((ext_vector_type(4)));

#define BATCH 16
#define MDIM 1024
#define NDIM 4096
#define KDIM 1024
#define BM 256
#define BN 256
#define BK 64
#define NKT (KDIM / BK)  // 16

__device__ __forceinline__ void gload_lds16(const void* g, void* l) {
  __builtin_amdgcn_global_load_lds(
      (const __attribute__((address_space(1))) void*)g,
      (__attribute__((address_space(3))) void*)l, 16, 0, 0);
}

#define BAR() __builtin_amdgcn_s_barrier()
#define SB() __builtin_amdgcn_sched_barrier(0)
#define FENCE() asm volatile("" ::: "memory")
#define LGKM0()                                        \
  do {                                                 \
    asm volatile("s_waitcnt lgkmcnt(0)" ::: "memory"); \
    SB();                                              \
  } while (0)
#define VMC8()                                         \
  do {                                                 \
    asm volatile("s_waitcnt vmcnt(8)" ::: "memory");   \
    SB();                                              \
  } while (0)
#define VMC0()                                         \
  do {                                                 \
    asm volatile("s_waitcnt vmcnt(0)" ::: "memory");   \
    SB();                                              \
  } while (0)

// ---------------------------------------------------------------------------
// Kernel 1: W~[b][o][i] bf16 into workspace (~10us).  (unchanged)
// ---------------------------------------------------------------------------
__global__ __launch_bounds__(256) void modw_kernel(
    const float* __restrict__ weight, const float* __restrict__ y,
    __bf16* __restrict__ wm) {
  const int blk = blockIdx.x;  // 16384
  const int b = blk & 15;
  const int o = blk >> 4;
  const int t = threadIdx.x;
  const float4 w4 = reinterpret_cast<const float4*>(weight + (size_t)o * KDIM)[t];
  const float4 y4 = reinterpret_cast<const float4*>(y + (size_t)b * KDIM)[t];
  const float p0 = w4.x * y4.x, p1 = w4.y * y4.y;
  const float p2 = w4.z * y4.z, p3 = w4.w * y4.w;
  float s = p0 * p0 + p1 * p1 + p2 * p2 + p3 * p3;
#pragma unroll
  for (int off = 32; off >= 1; off >>= 1) s += __shfl_xor(s, off, 64);
  __shared__ float ps[4];
  if ((t & 63) == 0) ps[t >> 6] = s;
  __syncthreads();
  const float tot = ps[0] + ps[1] + ps[2] + ps[3];
  const float scale = 0.03125f;  // 1/sqrt(1024)
  const float dn = scale * rsqrtf(scale * scale * tot + 1e-8f);
  bf16x4 v;
  v[0] = (__bf16)(p0 * dn);
  v[1] = (__bf16)(p1 * dn);
  v[2] = (__bf16)(p2 * dn);
  v[3] = (__bf16)(p3 * dn);
  *reinterpret_cast<bf16x4*>(wm + ((size_t)b * MDIM + o) * KDIM + t * 4) = v;
}

// ---------------------------------------------------------------------------
// Kernel 2: R6 structure (session best, 211.5us) with ONE change:
// FLOAT4-VECTORIZED B LOADS.  Thread->(n,k) ownership remapped from
// (1 n x 8 k-groups, 32 scalar dwords) to (4 n x 8 k, 8 x float4):
//   - same bytes, 4x fewer VMEM instructions (32->8) and addr-VALU ops
//   - VMEM queue shrinks: boundary wait becomes vmcnt(8) with the same
//     [stageA(t+1) 4 older | br(t+2) 8 younger] invariant
//   - LDS image bit-identical to R6 (same elements, same XOR swizzle,
//     same cvt rounding) -> numerics unchanged
//   - ds_write conflict-free: per 8-lane group, slot index
//     (lane&7)*16 ^ ((n_local&7)<<4) spans 8 distinct 16B slots
// Everything else (region rhythm, frag read-ahead, setprio, epilogue,
// XCD swizzle) is exactly R6.
// ---------------------------------------------------------------------------
__global__ __launch_bounds__(512, 2) void gemm_kernel(
    const __bf16* __restrict__ Wm, const float* __restrict__ E,
    float* __restrict__ out) {
  const int orig = blockIdx.x;  // 1024
  const int wg = (orig & 7) * 128 + (orig >> 3);  // bijective XCD swizzle
  const int mt = wg & 3;
  const int nt = (wg >> 2) & 15;
  const int b = wg >> 6;
  const int m0 = mt * BM, n0 = nt * BN;

  __shared__ __align__(16) char smem[131072];
  char* const A0_ = smem;
  char* const A1_ = smem + 32768;
  char* const B0_ = smem + 65536;
  char* const B1_ = smem + 98304;

  const int tid = threadIdx.x;  // 512
  const int lane = tid & 63;
  const int wid = tid >> 6;  // 0..7
  const int wr = wid >> 2;   // 0..1
  const int wc = wid & 3;    // 0..3
  const int ml = lane & 15;
  const int kg = lane >> 4;

  // ---- A staging ----
  const int arow = tid >> 3;                      // 0..63, +64/round
  const int aswz = ((tid & 7) ^ (arow & 7)) * 8;  // pre-swizzled k-elem off
  const __bf16* Ag = Wm + ((size_t)(b * MDIM + m0 + arow)) * KDIM + aswz;
  const int aldsOff = tid * 16;

  // ---- B staging: thread owns 4 consecutive n x 8 consecutive k ----
  const int nq = tid >> 3;   // 0..63 -> n = n0 + nq*4
  const int kgp = tid & 7;   // 0..7  -> k = kt*64 + kgp*8 + j
  typedef const __attribute__((address_space(1))) f32x4 gf32x4;
  gf32x4* Eg = (gf32x4*)(E + (size_t)b * KDIM * NDIM +
                         (size_t)(kgp * 8) * NDIM + n0 + nq * 4);
  // NDIM floats = NDIM/4 f32x4 per k-row
  int bwr[4];
#pragma unroll
  for (int nn = 0; nn < 4; ++nn) {
    const int n = nq * 4 + nn;
    bwr[nn] = n * 128 + ((kgp * 16) ^ ((n & 7) << 4));
  }

  // ---- compute-side fragment addressing ----
  const int colA = (kg * 16) ^ ((ml & 7) << 4);
  const int arB = (wr * 128 + ml) * 128;
  const int brB = (wc * 64 + ml) * 128;

  f32x4 acc[8][4];
#pragma unroll
  for (int i = 0; i < 8; ++i)
#pragma unroll
    for (int j = 0; j < 4; ++j) acc[i][j] = (f32x4){0.f, 0.f, 0.f, 0.f};

  auto stageA = [&](char* Ab, int kt) {
#pragma unroll
    for (int r = 0; r < 4; ++r)
      gload_lds16(Ag + (size_t)(64 * r) * KDIM + kt * BK,
                  Ab + aldsOff + r * 8192);
  };
  auto loadB = [&](f32x4 (&brr)[8], int kt) {
#pragma unroll
    for (int j = 0; j < 8; ++j)
      brr[j] = Eg[(size_t)(kt * BK + j) * (NDIM / 4)];
  };
  auto writeB = [&](char* Bb, f32x4 (&brr)[8]) {
#pragma unroll
    for (int nn = 0; nn < 4; ++nn) {
      bf16x8 v;
#pragma unroll
      for (int j = 0; j < 8; ++j) v[j] = (__bf16)brr[j][nn];
      *reinterpret_cast<bf16x8*>(Bb + bwr[nn]) = v;
    }
  };
  auto rdA = [&](bf16x8 (&d)[4], const char* Ab, int qm, int kk) {
#pragma unroll
    for (int i = 0; i < 4; ++i)
      d[i] = *reinterpret_cast<const bf16x8*>(Ab + arB + (qm * 4 + i) * 2048 +
                                              (colA ^ (kk * 64)));
  };
  auto rdB = [&](bf16x8 (&d)[4], const char* Bb, int kk) {
#pragma unroll
    for (int nf = 0; nf < 4; ++nf)
      d[nf] = *reinterpret_cast<const bf16x8*>(Bb + brB + nf * 2048 +
                                               (colA ^ (kk * 64)));
  };
  auto mfma16 = [&](bf16x8 (&a)[4], bf16x8 (&bv)[4], int qm) {
    __builtin_amdgcn_s_setprio(1);
#pragma unroll
    for (int i = 0; i < 4; ++i)
#pragma unroll
      for (int nf = 0; nf < 4; ++nf)
        acc[qm * 4 + i][nf] = __builtin_amdgcn_mfma_f32_16x16x32_bf16(
            a[i], bv[nf], acc[qm * 4 + i][nf], 0, 0, 0);
    __builtin_amdgcn_s_setprio(0);
  };

  f32x4 br[8];             // B reg-stage (32 VGPR, same as before)
  bf16x8 af0[4], af1[4];   // rotating frag slots
  bf16x8 bf0[4], bf1[4];

  // ---- prologue: tile0 into A0/B0 (full drain once); br <- tile1;
  //      pre-read R0 frags of tile0 ----
  {
    f32x4 brT[8];
    stageA(A0_, 0);  // queue [A0(4)]
    FENCE();
    loadB(brT, 0);     // [A0(4), brT(8)]
    writeB(B0_, brT);  // implicit vmcnt(0): all drained
    loadB(br, 1);      // [br1(8)] == loop-entry invariant
    LGKM0();
    BAR();
    rdA(af0, A0_, 0, 0);
    rdB(bf0, B0_, 0);
  }

  char* Ac = A0_;
  char* Ao = A1_;
  char* Bc = B0_;
  char* Bo = B1_;

#pragma unroll 1
  for (int t = 0; t < NKT; ++t) {
    const bool pf1 = (t + 1 < NKT);
    const bool pf2 = (t + 2 < NKT);

    // R0: read-ahead (q1,k0); publish B(t+1); MFMA q0k0
    rdA(af1, Ac, 1, 0);
    if (pf1) writeB(Bo, br);  // implicit wait: br(t+1), issued ~1 tile ago
    mfma16(af0, bf0, 0);

    // R1: read-ahead (k1),(q0,k1); stage A(t+1); prefetch br(t+2); MFMA q1k0
    rdB(bf1, Bc, 1);
    rdA(af0, Ac, 0, 1);
    if (pf1) stageA(Ao, t + 1);
    FENCE();  // pin VMEM order: stage older than br loads
    if (pf2) loadB(br, t + 2);
    mfma16(af1, bf0, 1);

    // R2: read-ahead (q1,k1); MFMA q0k1; single sync point
    rdA(af1, Ac, 1, 1);
    mfma16(af0, bf1, 0);
    LGKM0();  // my frag reads + my B ds_writes done
    if (pf2) {
      VMC8();  // queue [stageA(t+1) 4 | br(t+2) 8] -> drains the A stage
    } else {
      VMC0();  // tail: no br in flight; drain remaining stage
    }
    BAR();

    // R3: read-ahead tile t+1 frags from Ao/Bo; MFMA q1k1
    if (pf1) {
      rdA(af0, Ao, 0, 0);
      rdB(bf0, Bo, 0);
    }
    mfma16(af1, bf1, 1);

    char* ta = Ac; Ac = Ao; Ao = ta;
    char* tb = Bc; Bc = Bo; Bo = tb;
  }

  // ---- epilogue (unchanged) ----
  float* ob = out + ((size_t)(b * MDIM + m0 + wr * 128 + kg * 4)) * NDIM +
              n0 + wc * 64 + ml;
#pragma unroll
  for (int mf = 0; mf < 8; ++mf)
#pragma unroll
    for (int nf = 0; nf < 4; ++nf) {
      const f32x4 a = acc[mf][nf];
      float* p = ob + (size_t)mf * 16 * NDIM + nf * 16;
#pragma unroll
      for (int q = 0; q < 4; ++q) p[(size_t)q * NDIM] = a[q];
    }
}

extern "C" void kernel_launch(void* const* d_in, const int* in_sizes, int n_in,
                              void* d_out, int out_size, void* d_ws,
                              size_t ws_size, hipStream_t stream) {
  (void)in_sizes;
  (void)n_in;
  (void)out_size;
  (void)ws_size;
  const float* Efou = (const float*)d_in[0];
  const float* y = (const float*)d_in[1];
  const float* weight = (const float*)d_in[2];
  float* outp = (float*)d_out;
  __bf16* wm = (__bf16*)d_ws;  // 32 MB

  modw_kernel<<<dim3(BATCH * MDIM), dim3(256), 0, stream>>>(weight, y, wm);
  gemm_kernel<<<dim3(BATCH * (MDIM / BM) * (NDIM / BN)), dim3(512), 0,
                stream>>>(wm, Efou, outp);
}